// Round 1
// baseline (616.117 us; speedup 1.0000x reference)
//
#include <hip/hip_runtime.h>

#define BB 32
#define CC 256
#define CQK 32
#define LL 1024
#define OTOT 320   // CQK + CQK + C rows of fused W

// workspace layout in floats
#define WCAT_OFF 0
#define BCAT_OFF (OTOT * CC)           // 81920
#define QKV_OFF  (OTOT * CC + OTOT)    // 82240 (16B aligned)

// ---------------------------------------------------------------- pack W+b
__global__ __launch_bounds__(256) void pack_w_kernel(
    const float* __restrict__ Wq, const float* __restrict__ bq,
    const float* __restrict__ Wk, const float* __restrict__ bk,
    const float* __restrict__ Wv, const float* __restrict__ bv,
    float* __restrict__ Wcat, float* __restrict__ bcat) {
  int o = blockIdx.x;
  int c = threadIdx.x;
  float w = (o < CQK) ? Wq[o * CC + c]
          : (o < 2 * CQK) ? Wk[(o - CQK) * CC + c]
          : Wv[(o - 2 * CQK) * CC + c];
  Wcat[o * CC + c] = w;
  if (c == 0) {
    bcat[o] = (o < CQK) ? bq[o] : (o < 2 * CQK) ? bk[o - CQK] : bv[o - 2 * CQK];
  }
}

// ------------------------------------------------- QKV projection (fused)
// qkv[b][o][l] = bcat[o] + sum_c Wcat[o][c] * x[b][c][l], o in [0,320)
#define PPITCH 68  // 64 + 4 pad, keeps float4 alignment
__global__ __launch_bounds__(256) void proj_kernel(
    const float* __restrict__ x, const float* __restrict__ Wcat,
    const float* __restrict__ bcat, float* __restrict__ qkv) {
  __shared__ float ws[32][PPITCH];  // [kk][o]
  __shared__ float xs[32][PPITCH];  // [kk][l]
  int b = blockIdx.z;
  int o0 = blockIdx.y * 64;
  int l0 = blockIdx.x * 64;
  int tid = threadIdx.x;
  int tx = tid & 15, ty = tid >> 4;
  const float* xb = x + (size_t)b * CC * LL;
  float acc[4][4] = {};

  for (int c0 = 0; c0 < CC; c0 += 32) {
    __syncthreads();
    {
      int o = tid >> 5;       // 0..7
      int kk = tid & 31;      // 0..31
#pragma unroll
      for (int r = 0; r < 8; ++r)
        ws[kk][o + 8 * r] = Wcat[(o0 + o + 8 * r) * CC + c0 + kk];
      int l = tid & 63;       // 0..63
      int k4 = tid >> 6;      // 0..3
#pragma unroll
      for (int r = 0; r < 8; ++r)
        xs[k4 + 4 * r][l] = xb[(size_t)(c0 + k4 + 4 * r) * LL + l0 + l];
    }
    __syncthreads();
#pragma unroll 8
    for (int kk = 0; kk < 32; ++kk) {
      float a[4], bvv[4];
      *(float4*)a = *(const float4*)&ws[kk][ty * 4];
      *(float4*)bvv = *(const float4*)&xs[kk][tx * 4];
#pragma unroll
      for (int i = 0; i < 4; ++i)
#pragma unroll
        for (int j = 0; j < 4; ++j)
          acc[i][j] = fmaf(a[i], bvv[j], acc[i][j]);
    }
  }
#pragma unroll
  for (int i = 0; i < 4; ++i) {
    int o = o0 + ty * 4 + i;
    float bias = bcat[o];
    float4 r;
    r.x = acc[i][0] + bias;
    r.y = acc[i][1] + bias;
    r.z = acc[i][2] + bias;
    r.w = acc[i][3] + bias;
    *(float4*)&qkv[((size_t)b * OTOT + o) * LL + l0 + tx * 4] = r;
  }
}

// ----------------------------------------------------- scores = q^T k (K=32)
__global__ __launch_bounds__(256) void scores_kernel(
    const float* __restrict__ qkv, float* __restrict__ att) {
  __shared__ float qs[32][PPITCH];  // [d][i]
  __shared__ float ks[32][PPITCH];  // [d][j]
  int b = blockIdx.z;
  int i0 = blockIdx.y * 64;
  int j0 = blockIdx.x * 64;
  int tid = threadIdx.x;
  int tx = tid & 15, ty = tid >> 4;
  const float* qb = qkv + (size_t)b * OTOT * LL;            // rows 0..31
  const float* kb = qkv + ((size_t)b * OTOT + CQK) * LL;    // rows 32..63
  {
    int l = tid & 63;
    int k4 = tid >> 6;
#pragma unroll
    for (int r = 0; r < 8; ++r) {
      int kk = k4 + 4 * r;
      qs[kk][l] = qb[(size_t)kk * LL + i0 + l];
      ks[kk][l] = kb[(size_t)kk * LL + j0 + l];
    }
  }
  __syncthreads();
  float acc[4][4] = {};
#pragma unroll 8
  for (int kk = 0; kk < 32; ++kk) {
    float a[4], bvv[4];
    *(float4*)a = *(const float4*)&qs[kk][ty * 4];
    *(float4*)bvv = *(const float4*)&ks[kk][tx * 4];
#pragma unroll
    for (int i = 0; i < 4; ++i)
#pragma unroll
      for (int j = 0; j < 4; ++j)
        acc[i][j] = fmaf(a[i], bvv[j], acc[i][j]);
  }
#pragma unroll
  for (int i = 0; i < 4; ++i) {
    float4 r;
    r.x = acc[i][0]; r.y = acc[i][1]; r.z = acc[i][2]; r.w = acc[i][3];
    *(float4*)&att[(size_t)b * LL * LL + (size_t)(i0 + ty * 4 + i) * LL + j0 + tx * 4] = r;
  }
}

// --------------------------------------------------------- row softmax in place
__global__ __launch_bounds__(256) void softmax_kernel(float* __restrict__ att) {
  float* p = att + (size_t)blockIdx.x * LL;
  int t = threadIdx.x;
  float4 v = *(float4*)&p[t * 4];
  float m = fmaxf(fmaxf(v.x, v.y), fmaxf(v.z, v.w));
#pragma unroll
  for (int k = 32; k >= 1; k >>= 1) m = fmaxf(m, __shfl_xor(m, k));
  __shared__ float redm[4];
  __shared__ float reds[4];
  int w = t >> 6, lane = t & 63;
  if (lane == 0) redm[w] = m;
  __syncthreads();
  m = fmaxf(fmaxf(redm[0], redm[1]), fmaxf(redm[2], redm[3]));
  float4 e;
  e.x = __expf(v.x - m);
  e.y = __expf(v.y - m);
  e.z = __expf(v.z - m);
  e.w = __expf(v.w - m);
  float s = e.x + e.y + e.z + e.w;
#pragma unroll
  for (int k = 32; k >= 1; k >>= 1) s += __shfl_xor(s, k);
  if (lane == 0) reds[w] = s;
  __syncthreads();
  s = reds[0] + reds[1] + reds[2] + reds[3];
  float inv = 1.0f / s;
  e.x *= inv; e.y *= inv; e.z *= inv; e.w *= inv;
  *(float4*)&p[t * 4] = e;
}

// ---------------------- out[b][c][m] = gamma * sum_l v[c][l]*att[m][l] + x
#define OPITCH 36  // 32 + 4 pad, float4-aligned
__global__ __launch_bounds__(256) void out_kernel(
    const float* __restrict__ qkv, const float* __restrict__ att,
    const float* __restrict__ x, const float* __restrict__ gamma,
    float* __restrict__ out) {
  __shared__ float vs[64][OPITCH];   // [c][kk]
  __shared__ float as2[64][OPITCH];  // [m][kk]
  int b = blockIdx.z;
  int c0 = blockIdx.y * 64;
  int m0 = blockIdx.x * 64;
  int tid = threadIdx.x;
  int tx = tid & 15, ty = tid >> 4;
  const float* vb = qkv + ((size_t)b * OTOT + 2 * CQK) * LL;  // v rows 64..319
  const float* ab = att + (size_t)b * LL * LL;
  float acc[4][4] = {};

  int c_ld = tid >> 3;        // 0..31
  int k4 = (tid & 7) * 4;     // 0,4,...,28

  for (int l1 = 0; l1 < LL; l1 += 32) {
    float4 va0 = *(const float4*)&vb[(size_t)(c0 + c_ld) * LL + l1 + k4];
    float4 va1 = *(const float4*)&vb[(size_t)(c0 + c_ld + 32) * LL + l1 + k4];
    float4 aa0 = *(const float4*)&ab[(size_t)(m0 + c_ld) * LL + l1 + k4];
    float4 aa1 = *(const float4*)&ab[(size_t)(m0 + c_ld + 32) * LL + l1 + k4];
    __syncthreads();
    *(float4*)&vs[c_ld][k4] = va0;
    *(float4*)&vs[c_ld + 32][k4] = va1;
    *(float4*)&as2[c_ld][k4] = aa0;
    *(float4*)&as2[c_ld + 32][k4] = aa1;
    __syncthreads();
#pragma unroll
    for (int kq = 0; kq < 8; ++kq) {
      float av[4][4], bv[4][4];
#pragma unroll
      for (int i = 0; i < 4; ++i)
        *(float4*)av[i] = *(const float4*)&vs[ty + 16 * i][kq * 4];
#pragma unroll
      for (int j = 0; j < 4; ++j)
        *(float4*)bv[j] = *(const float4*)&as2[tx + 16 * j][kq * 4];
#pragma unroll
      for (int i = 0; i < 4; ++i)
#pragma unroll
        for (int j = 0; j < 4; ++j)
#pragma unroll
          for (int q = 0; q < 4; ++q)
            acc[i][j] = fmaf(av[i][q], bv[j][q], acc[i][j]);
    }
  }

  float g = gamma[0];
#pragma unroll
  for (int i = 0; i < 4; ++i) {
    int c = c0 + ty + 16 * i;
#pragma unroll
    for (int j = 0; j < 4; ++j) {
      int m = m0 + tx + 16 * j;
      size_t idx = ((size_t)b * CC + c) * LL + m;
      out[idx] = fmaf(g, acc[i][j], x[idx]);
    }
  }
}

extern "C" void kernel_launch(void* const* d_in, const int* in_sizes, int n_in,
                              void* d_out, int out_size, void* d_ws, size_t ws_size,
                              hipStream_t stream) {
  const float* x = (const float*)d_in[0];
  const float* Wq = (const float*)d_in[1];
  const float* bq = (const float*)d_in[2];
  const float* Wk = (const float*)d_in[3];
  const float* bk = (const float*)d_in[4];
  const float* Wv = (const float*)d_in[5];
  const float* bv = (const float*)d_in[6];
  const float* gamma = (const float*)d_in[7];

  float* out = (float*)d_out;
  float* att = out + (size_t)BB * CC * LL;  // attention output region

  float* wsf = (float*)d_ws;
  float* Wcat = wsf + WCAT_OFF;
  float* bcat = wsf + BCAT_OFF;
  float* qkv = wsf + QKV_OFF;

  pack_w_kernel<<<dim3(OTOT), dim3(CC), 0, stream>>>(Wq, bq, Wk, bk, Wv, bv, Wcat, bcat);
  proj_kernel<<<dim3(LL / 64, OTOT / 64, BB), dim3(256), 0, stream>>>(x, Wcat, bcat, qkv);
  scores_kernel<<<dim3(LL / 64, LL / 64, BB), dim3(256), 0, stream>>>(qkv, att);
  softmax_kernel<<<dim3(BB * LL), dim3(256), 0, stream>>>(att);
  out_kernel<<<dim3(LL / 64, CC / 64, BB), dim3(256), 0, stream>>>(qkv, att, x, gamma, out);
}

// Round 2
// 361.569 us; speedup vs baseline: 1.7040x; 1.7040x over previous
//
#include <hip/hip_runtime.h>
#include <hip/hip_bf16.h>

#define BB 32
#define CC 256
#define CQK 32
#define LL 1024
#define OTOT 320   // CQK + CQK + C rows of fused W

// workspace layout
// float region:
#define WCAT_OFF 0
#define BCAT_OFF (OTOT * CC)            // 81920
#define QK_OFF   (BCAT_OFF + OTOT)      // 82240 (16B aligned)
#define QK_SIZE  (BB * 64 * LL)         // 2097152 floats (q rows 0..31, k rows 32..63 per batch)
#define US_BASE  (QK_OFF + QK_SIZE)     // float idx 2179392 -> byte 8717568 (16B aligned)
// ushort region (offsets in ushorts from US_BASE):
#define VBF_OFF   0
#define ATTBF_OFF ((size_t)BB * CC * LL)  // 8388608

typedef __bf16 bf16x8 __attribute__((ext_vector_type(8)));
typedef float f32x4 __attribute__((ext_vector_type(4)));

__device__ inline void async_ld16(const void* g, void* l) {
  __builtin_amdgcn_global_load_lds(
      (const __attribute__((address_space(1))) void*)g,
      (__attribute__((address_space(3))) void*)l, 16, 0, 0);
}

// ---------------------------------------------------------------- pack W+b
__global__ __launch_bounds__(256) void pack_w_kernel(
    const float* __restrict__ Wq, const float* __restrict__ bq,
    const float* __restrict__ Wk, const float* __restrict__ bk,
    const float* __restrict__ Wv, const float* __restrict__ bv,
    float* __restrict__ Wcat, float* __restrict__ bcat) {
  int o = blockIdx.x;
  int c = threadIdx.x;
  float w = (o < CQK) ? Wq[o * CC + c]
          : (o < 2 * CQK) ? Wk[(o - CQK) * CC + c]
          : Wv[(o - 2 * CQK) * CC + c];
  Wcat[o * CC + c] = w;
  if (c == 0) {
    bcat[o] = (o < CQK) ? bq[o] : (o < 2 * CQK) ? bk[o - CQK] : bv[o - 2 * CQK];
  }
}

// ------------------------------------------------- QKV projection (fused)
// o<64 -> qk fp32; o>=64 -> vbf bf16
#define PPITCH 68  // 64 + 4 pad, keeps float4 alignment
__global__ __launch_bounds__(256) void proj_kernel(
    const float* __restrict__ x, const float* __restrict__ Wcat,
    const float* __restrict__ bcat, float* __restrict__ qk,
    ushort* __restrict__ vbf) {
  __shared__ float ws[32][PPITCH];  // [kk][o]
  __shared__ float xs[32][PPITCH];  // [kk][l]
  int b = blockIdx.z;
  int o0 = blockIdx.y * 64;
  int l0 = blockIdx.x * 64;
  int tid = threadIdx.x;
  int tx = tid & 15, ty = tid >> 4;
  const float* xb = x + (size_t)b * CC * LL;
  float acc[4][4] = {};

  for (int c0 = 0; c0 < CC; c0 += 32) {
    __syncthreads();
    {
      int o = tid >> 5;       // 0..7
      int kk = tid & 31;      // 0..31
#pragma unroll
      for (int r = 0; r < 8; ++r)
        ws[kk][o + 8 * r] = Wcat[(o0 + o + 8 * r) * CC + c0 + kk];
      int l = tid & 63;       // 0..63
      int k4 = tid >> 6;      // 0..3
#pragma unroll
      for (int r = 0; r < 8; ++r)
        xs[k4 + 4 * r][l] = xb[(size_t)(c0 + k4 + 4 * r) * LL + l0 + l];
    }
    __syncthreads();
#pragma unroll 8
    for (int kk = 0; kk < 32; ++kk) {
      float a[4], bvv[4];
      *(float4*)a = *(const float4*)&ws[kk][ty * 4];
      *(float4*)bvv = *(const float4*)&xs[kk][tx * 4];
#pragma unroll
      for (int i = 0; i < 4; ++i)
#pragma unroll
        for (int j = 0; j < 4; ++j)
          acc[i][j] = fmaf(a[i], bvv[j], acc[i][j]);
    }
  }
#pragma unroll
  for (int i = 0; i < 4; ++i) {
    int o = o0 + ty * 4 + i;
    float bias = bcat[o];
    float4 r;
    r.x = acc[i][0] + bias;
    r.y = acc[i][1] + bias;
    r.z = acc[i][2] + bias;
    r.w = acc[i][3] + bias;
    if (o0 < 64) {
      *(float4*)&qk[((size_t)b * 64 + o) * LL + l0 + tx * 4] = r;
    } else {
      union { ushort4 u; __hip_bfloat16 h[4]; } cv;
      cv.h[0] = __float2bfloat16(r.x);
      cv.h[1] = __float2bfloat16(r.y);
      cv.h[2] = __float2bfloat16(r.z);
      cv.h[3] = __float2bfloat16(r.w);
      *(ushort4*)&vbf[((size_t)b * CC + (o - 64)) * LL + l0 + tx * 4] = cv.u;
    }
  }
}

// ----------------------------------------------------- scores = q^T k (K=32)
__global__ __launch_bounds__(256) void scores_kernel(
    const float* __restrict__ qk, float* __restrict__ att) {
  __shared__ float qs[32][PPITCH];  // [d][i]
  __shared__ float ks[32][PPITCH];  // [d][j]
  int b = blockIdx.z;
  int i0 = blockIdx.y * 64;
  int j0 = blockIdx.x * 64;
  int tid = threadIdx.x;
  int tx = tid & 15, ty = tid >> 4;
  const float* qb = qk + (size_t)b * 64 * LL;        // rows 0..31
  const float* kb = qb + (size_t)CQK * LL;           // rows 32..63
  {
    int l = tid & 63;
    int k4 = tid >> 6;
#pragma unroll
    for (int r = 0; r < 8; ++r) {
      int kk = k4 + 4 * r;
      qs[kk][l] = qb[(size_t)kk * LL + i0 + l];
      ks[kk][l] = kb[(size_t)kk * LL + j0 + l];
    }
  }
  __syncthreads();
  float acc[4][4] = {};
#pragma unroll 8
  for (int kk = 0; kk < 32; ++kk) {
    float a[4], bvv[4];
    *(float4*)a = *(const float4*)&qs[kk][ty * 4];
    *(float4*)bvv = *(const float4*)&ks[kk][tx * 4];
#pragma unroll
    for (int i = 0; i < 4; ++i)
#pragma unroll
      for (int j = 0; j < 4; ++j)
        acc[i][j] = fmaf(a[i], bvv[j], acc[i][j]);
  }
#pragma unroll
  for (int i = 0; i < 4; ++i) {
    float4 r;
    r.x = acc[i][0]; r.y = acc[i][1]; r.z = acc[i][2]; r.w = acc[i][3];
    *(float4*)&att[(size_t)b * LL * LL + (size_t)(i0 + ty * 4 + i) * LL + j0 + tx * 4] = r;
  }
}

// ------------------------------- row softmax in place + bf16 copy to ws
__global__ __launch_bounds__(256) void softmax_kernel(
    float* __restrict__ att, ushort* __restrict__ attbf) {
  float* p = att + (size_t)blockIdx.x * LL;
  ushort* pb = attbf + (size_t)blockIdx.x * LL;
  int t = threadIdx.x;
  float4 v = *(float4*)&p[t * 4];
  float m = fmaxf(fmaxf(v.x, v.y), fmaxf(v.z, v.w));
#pragma unroll
  for (int k = 32; k >= 1; k >>= 1) m = fmaxf(m, __shfl_xor(m, k));
  __shared__ float redm[4];
  __shared__ float reds[4];
  int w = t >> 6, lane = t & 63;
  if (lane == 0) redm[w] = m;
  __syncthreads();
  m = fmaxf(fmaxf(redm[0], redm[1]), fmaxf(redm[2], redm[3]));
  float4 e;
  e.x = __expf(v.x - m);
  e.y = __expf(v.y - m);
  e.z = __expf(v.z - m);
  e.w = __expf(v.w - m);
  float s = e.x + e.y + e.z + e.w;
#pragma unroll
  for (int k = 32; k >= 1; k >>= 1) s += __shfl_xor(s, k);
  if (lane == 0) reds[w] = s;
  __syncthreads();
  s = reds[0] + reds[1] + reds[2] + reds[3];
  float inv = 1.0f / s;
  e.x *= inv; e.y *= inv; e.z *= inv; e.w *= inv;
  *(float4*)&p[t * 4] = e;
  union { ushort4 u; __hip_bfloat16 h[4]; } cv;
  cv.h[0] = __float2bfloat16(e.x);
  cv.h[1] = __float2bfloat16(e.y);
  cv.h[2] = __float2bfloat16(e.z);
  cv.h[3] = __float2bfloat16(e.w);
  *(ushort4*)&pb[t * 4] = cv.u;
}

// ------------- out[b][c][m] = gamma * sum_l v[c][l]*att[m][l] + x  (bf16 MFMA)
// A = vbf[b] : [256][1024] bf16 row-major (M x K)
// B^T = attbf[b] : [1024][1024] bf16 row-major (N x K)
// 128x128 tile, BK=32, 4 waves, each wave 64x64 (4x4 MFMAs of 16x16x32)
__global__ __launch_bounds__(256) void out_mfma_kernel(
    const ushort* __restrict__ vbf, const ushort* __restrict__ attbf,
    const float* __restrict__ x, const float* __restrict__ gamma,
    float* __restrict__ out) {
  __shared__ ushort As[128 * 32];
  __shared__ ushort Bs[128 * 32];
  int b = blockIdx.z;
  int c0 = blockIdx.y * 128;
  int m0 = blockIdx.x * 128;
  int tid = threadIdx.x;
  int wave = tid >> 6, lane = tid & 63;
  int quad = lane >> 4, ln = lane & 15;
  int wr = (wave >> 1) * 64;  // wave M offset in tile
  int wc = (wave & 1) * 64;   // wave N offset in tile

  const ushort* vb = vbf + (size_t)b * CC * LL;
  const ushort* ab = attbf + (size_t)b * LL * LL;

  // staging chunk ci = s*256 + tid; row = ci>>2 (0..127), col8 = (ci&3)*8
  int r0 = tid >> 2;            // 0..63
  int r1 = r0 + 64;             // 64..127
  int cq = (tid & 3) * 8;       // 0,8,16,24
  // wave-uniform LDS bases (lane lands at base + lane*16B)
  ushort* lA0 = As + (size_t)(wave * 64) * 8;
  ushort* lA1 = As + (size_t)(256 + wave * 64) * 8;
  ushort* lB0 = Bs + (size_t)(wave * 64) * 8;
  ushort* lB1 = Bs + (size_t)(256 + wave * 64) * 8;

  f32x4 acc[4][4];
#pragma unroll
  for (int i = 0; i < 4; ++i)
#pragma unroll
    for (int j = 0; j < 4; ++j)
      acc[i][j] = {0.f, 0.f, 0.f, 0.f};

  for (int kt = 0; kt < LL; kt += 32) {
    __syncthreads();  // protect LDS from overwrite while prior reads in flight
    async_ld16(vb + (size_t)(c0 + r0) * LL + kt + cq, lA0);
    async_ld16(vb + (size_t)(c0 + r1) * LL + kt + cq, lA1);
    async_ld16(ab + (size_t)(m0 + r0) * LL + kt + cq, lB0);
    async_ld16(ab + (size_t)(m0 + r1) * LL + kt + cq, lB1);
    __syncthreads();  // drains vmcnt(0): staging complete

    bf16x8 af[4], bfr[4];
#pragma unroll
    for (int i = 0; i < 4; ++i)
      af[i] = *(const bf16x8*)&As[(size_t)(wr + i * 16 + ln) * 32 + quad * 8];
#pragma unroll
    for (int j = 0; j < 4; ++j)
      bfr[j] = *(const bf16x8*)&Bs[(size_t)(wc + j * 16 + ln) * 32 + quad * 8];
#pragma unroll
    for (int i = 0; i < 4; ++i)
#pragma unroll
      for (int j = 0; j < 4; ++j)
        acc[i][j] = __builtin_amdgcn_mfma_f32_16x16x32_bf16(af[i], bfr[j], acc[i][j], 0, 0, 0);
  }

  float g = gamma[0];
  const float* xb = x + (size_t)b * CC * LL;
  float* ob = out + (size_t)b * CC * LL;
#pragma unroll
  for (int i = 0; i < 4; ++i) {
#pragma unroll
    for (int r = 0; r < 4; ++r) {
      int c = c0 + wr + i * 16 + quad * 4 + r;
#pragma unroll
      for (int j = 0; j < 4; ++j) {
        int m = m0 + wc + j * 16 + ln;
        size_t idx = (size_t)c * LL + m;
        ob[idx] = fmaf(g, acc[i][j][r], xb[idx]);
      }
    }
  }
}

extern "C" void kernel_launch(void* const* d_in, const int* in_sizes, int n_in,
                              void* d_out, int out_size, void* d_ws, size_t ws_size,
                              hipStream_t stream) {
  const float* x = (const float*)d_in[0];
  const float* Wq = (const float*)d_in[1];
  const float* bq = (const float*)d_in[2];
  const float* Wk = (const float*)d_in[3];
  const float* bk = (const float*)d_in[4];
  const float* Wv = (const float*)d_in[5];
  const float* bv = (const float*)d_in[6];
  const float* gamma = (const float*)d_in[7];

  float* out = (float*)d_out;
  float* att = out + (size_t)BB * CC * LL;  // attention output region

  float* wsf = (float*)d_ws;
  float* Wcat = wsf + WCAT_OFF;
  float* bcat = wsf + BCAT_OFF;
  float* qk = wsf + QK_OFF;
  ushort* usbase = (ushort*)(wsf + US_BASE);
  ushort* vbf = usbase + VBF_OFF;
  ushort* attbf = usbase + ATTBF_OFF;

  pack_w_kernel<<<dim3(OTOT), dim3(CC), 0, stream>>>(Wq, bq, Wk, bk, Wv, bv, Wcat, bcat);
  proj_kernel<<<dim3(LL / 64, OTOT / 64, BB), dim3(256), 0, stream>>>(x, Wcat, bcat, qk, vbf);
  scores_kernel<<<dim3(LL / 64, LL / 64, BB), dim3(256), 0, stream>>>(qk, att);
  softmax_kernel<<<dim3(BB * LL), dim3(256), 0, stream>>>(att, attbf);
  out_mfma_kernel<<<dim3(LL / 128, CC / 128, BB), dim3(256), 0, stream>>>(vbf, attbf, x, gamma, out);
}

// Round 3
// 316.139 us; speedup vs baseline: 1.9489x; 1.1437x over previous
//
#include <hip/hip_runtime.h>
#include <hip/hip_bf16.h>

#define BB 32
#define CC 256
#define CQK 32
#define LL 1024
#define OTOT 320

// ---------------- workspace layout ----------------
// float region:
#define WCAT_OFF 0
#define BCAT_OFF (OTOT * CC)                 // 81920
#define QK_OFF   (BCAT_OFF + OTOT)           // 82240
#define QK_SIZE  (BB * 64 * LL)              // 2097152
#define US_BASE  (QK_OFF + QK_SIZE)          // 2179392 floats (byte 8717568, 16B aligned)
// ushort region (offsets in ushorts from US_BASE):
#define VBF_OFF   ((size_t)0)
#define ATTBF_OFF ((size_t)BB * CC * LL)                  // 8388608
#define WVBF_OFF  (ATTBF_OFF + (size_t)BB * LL * LL)      // 41943040
#define XT_OFF    (WVBF_OFF + (size_t)CC * CC)            // 42008576
#define KTH_OFF   (XT_OFF + (size_t)BB * LL * CC)         // 50397184
#define KTL_OFF   (KTH_OFF + (size_t)BB * LL * 32)        // 51445760

typedef __bf16 bf16x8 __attribute__((ext_vector_type(8)));
typedef float f32x4 __attribute__((ext_vector_type(4)));

__device__ inline void async_ld16(const void* g, void* l) {
  __builtin_amdgcn_global_load_lds(
      (const __attribute__((address_space(1))) void*)g,
      (__attribute__((address_space(3))) void*)l, 16, 0, 0);
}

__device__ inline ushort f2bu(float f) {
  union { __hip_bfloat16 h; ushort u; } c;
  c.h = __float2bfloat16(f);
  return c.u;
}
__device__ inline float bu2f(ushort u) {
  union { __hip_bfloat16 h; ushort u; } c;
  c.u = u;
  return __bfloat162float(c.h);
}

// ---------------------------------------------------------------- pack W+b
__global__ __launch_bounds__(256) void pack_w_kernel(
    const float* __restrict__ Wq, const float* __restrict__ bq,
    const float* __restrict__ Wk, const float* __restrict__ bk,
    const float* __restrict__ Wv, const float* __restrict__ bv,
    float* __restrict__ Wcat, float* __restrict__ bcat,
    ushort* __restrict__ Wvbf) {
  int o = blockIdx.x;
  int c = threadIdx.x;
  float w = (o < CQK) ? Wq[o * CC + c]
          : (o < 2 * CQK) ? Wk[(o - CQK) * CC + c]
          : Wv[(o - 2 * CQK) * CC + c];
  Wcat[o * CC + c] = w;
  if (o >= 64) Wvbf[(o - 64) * CC + c] = f2bu(w);
  if (c == 0) {
    bcat[o] = (o < CQK) ? bq[o] : (o < 2 * CQK) ? bk[o - CQK] : bv[o - 2 * CQK];
  }
}

// -------------------------------------------- x transpose: [b][c][l] -> bf16 [b][l][c]
__global__ __launch_bounds__(256) void xT_kernel(
    const float* __restrict__ x, ushort* __restrict__ xT) {
  __shared__ float t[64][65];
  int b = blockIdx.z, c0 = blockIdx.y * 64, l0 = blockIdx.x * 64;
  int tid = threadIdx.x;
  int r = tid >> 4, c4 = (tid & 15) * 4;
  const float* xb = x + ((size_t)b * CC + c0) * LL + l0;
#pragma unroll
  for (int i = 0; i < 4; ++i) {
    float4 v = *(const float4*)&xb[(size_t)(r + i * 16) * LL + c4];
    t[r + i * 16][c4 + 0] = v.x;
    t[r + i * 16][c4 + 1] = v.y;
    t[r + i * 16][c4 + 2] = v.z;
    t[r + i * 16][c4 + 3] = v.w;
  }
  __syncthreads();
  ushort* xo = xT + ((size_t)b * LL + l0) * CC + c0;
#pragma unroll
  for (int i = 0; i < 4; ++i) {
    int l = r + i * 16;
    ushort4 u;
    u.x = f2bu(t[c4 + 0][l]);
    u.y = f2bu(t[c4 + 1][l]);
    u.z = f2bu(t[c4 + 2][l]);
    u.w = f2bu(t[c4 + 3][l]);
    *(ushort4*)&xo[(size_t)l * CC + c4] = u;
  }
}

// ------------------------------------------------- q/k projection (fp32 VALU)
#define PPITCH 68
__global__ __launch_bounds__(256) void proj_qk_kernel(
    const float* __restrict__ x, const float* __restrict__ Wcat,
    const float* __restrict__ bcat, float* __restrict__ qk) {
  __shared__ float ws[32][PPITCH];
  __shared__ float xs[32][PPITCH];
  int b = blockIdx.z;
  int l0 = blockIdx.x * 64;
  int tid = threadIdx.x;
  int tx = tid & 15, ty = tid >> 4;
  const float* xb = x + (size_t)b * CC * LL;
  float acc[4][4] = {};

  for (int c0 = 0; c0 < CC; c0 += 32) {
    __syncthreads();
    {
      int o = tid >> 5;
      int kk = tid & 31;
#pragma unroll
      for (int r = 0; r < 8; ++r)
        ws[kk][o + 8 * r] = Wcat[(o + 8 * r) * CC + c0 + kk];
      int l = tid & 63;
      int k4 = tid >> 6;
#pragma unroll
      for (int r = 0; r < 8; ++r)
        xs[k4 + 4 * r][l] = xb[(size_t)(c0 + k4 + 4 * r) * LL + l0 + l];
    }
    __syncthreads();
#pragma unroll 8
    for (int kk = 0; kk < 32; ++kk) {
      float a[4], bvv[4];
      *(float4*)a = *(const float4*)&ws[kk][ty * 4];
      *(float4*)bvv = *(const float4*)&xs[kk][tx * 4];
#pragma unroll
      for (int i = 0; i < 4; ++i)
#pragma unroll
        for (int j = 0; j < 4; ++j)
          acc[i][j] = fmaf(a[i], bvv[j], acc[i][j]);
    }
  }
#pragma unroll
  for (int i = 0; i < 4; ++i) {
    int o = ty * 4 + i;
    float bias = bcat[o];
    float4 r;
    r.x = acc[i][0] + bias;
    r.y = acc[i][1] + bias;
    r.z = acc[i][2] + bias;
    r.w = acc[i][3] + bias;
    *(float4*)&qk[((size_t)b * 64 + o) * LL + l0 + tx * 4] = r;
  }
}

// ---------------- pack k rows into B-fragment order, hi/lo bf16
// kTp[b][jt][(q*16+ln)*8+jj] = k[b][k=q*8+jj][j=jt*16+ln]
__global__ __launch_bounds__(256) void kT_pack_kernel(
    const float* __restrict__ qk, ushort* __restrict__ kth,
    ushort* __restrict__ ktl) {
  __shared__ float ks[32][257];
  int b = blockIdx.y, jg = blockIdx.x;  // col group of 256
  int tid = threadIdx.x;
  const float* kb = qk + ((size_t)b * 64 + CQK) * LL + jg * 256;
#pragma unroll
  for (int i = 0; i < 8; ++i) {
    int row = i * 4 + (tid >> 6);
    int col4 = (tid & 63) * 4;
    float4 v = *(const float4*)&kb[(size_t)row * LL + col4];
    ks[row][col4 + 0] = v.x;
    ks[row][col4 + 1] = v.y;
    ks[row][col4 + 2] = v.z;
    ks[row][col4 + 3] = v.w;
  }
  __syncthreads();
#pragma unroll
  for (int rep = 0; rep < 4; ++rep) {
    int idx = rep * 256 + tid;            // 0..1023
    int jt_l = idx >> 6;                  // 0..15
    int q = (idx >> 4) & 3;
    int l16 = idx & 15;
    ushort h[8], lo[8];
#pragma unroll
    for (int jj = 0; jj < 8; ++jj) {
      float v = ks[q * 8 + jj][jt_l * 16 + l16];
      ushort hh = f2bu(v);
      h[jj] = hh;
      lo[jj] = f2bu(v - bu2f(hh));
    }
    size_t off = (((size_t)b * 64 + jg * 16 + jt_l) * 64 + (idx & 63)) * 8;
    *(ushort4*)&kth[off] = *(ushort4*)&h[0];
    *(ushort4*)&kth[off + 4] = *(ushort4*)&h[4];
    *(ushort4*)&ktl[off] = *(ushort4*)&lo[0];
    *(ushort4*)&ktl[off + 4] = *(ushort4*)&lo[4];
  }
}

// ---------------- v projection: vbf[b][c][l] = bf16( Wv·x + bv ), MFMA
__global__ __launch_bounds__(256) void v_mfma_kernel(
    const ushort* __restrict__ Wvbf, const ushort* __restrict__ xT,
    const float* __restrict__ bv, ushort* __restrict__ vbf) {
  __shared__ ushort As[128 * 32];
  __shared__ ushort Bs[128 * 32];
  int b = blockIdx.z;
  int c0 = blockIdx.y * 128;
  int l0 = blockIdx.x * 128;
  int tid = threadIdx.x;
  int wave = tid >> 6, lane = tid & 63;
  int quad = lane >> 4, ln = lane & 15;
  int wr = (wave >> 1) * 64;
  int wc = (wave & 1) * 64;
  const ushort* xb = xT + (size_t)b * LL * CC;
  int r0 = tid >> 2, r1 = r0 + 64;
  int cq = (tid & 3) * 8;
  ushort* lA0 = As + (size_t)(wave * 64) * 8;
  ushort* lA1 = As + (size_t)(256 + wave * 64) * 8;
  ushort* lB0 = Bs + (size_t)(wave * 64) * 8;
  ushort* lB1 = Bs + (size_t)(256 + wave * 64) * 8;

  f32x4 acc[4][4];
#pragma unroll
  for (int i = 0; i < 4; ++i)
#pragma unroll
    for (int j = 0; j < 4; ++j) acc[i][j] = {0.f, 0.f, 0.f, 0.f};

  for (int kt = 0; kt < CC; kt += 32) {
    __syncthreads();
    async_ld16(Wvbf + (size_t)(c0 + r0) * CC + kt + cq, lA0);
    async_ld16(Wvbf + (size_t)(c0 + r1) * CC + kt + cq, lA1);
    async_ld16(xb + (size_t)(l0 + r0) * CC + kt + cq, lB0);
    async_ld16(xb + (size_t)(l0 + r1) * CC + kt + cq, lB1);
    __syncthreads();
    bf16x8 af[4], bfr[4];
#pragma unroll
    for (int i = 0; i < 4; ++i)
      af[i] = *(const bf16x8*)&As[(size_t)(wr + i * 16 + ln) * 32 + quad * 8];
#pragma unroll
    for (int j = 0; j < 4; ++j)
      bfr[j] = *(const bf16x8*)&Bs[(size_t)(wc + j * 16 + ln) * 32 + quad * 8];
#pragma unroll
    for (int i = 0; i < 4; ++i)
#pragma unroll
      for (int j = 0; j < 4; ++j)
        acc[i][j] = __builtin_amdgcn_mfma_f32_16x16x32_bf16(af[i], bfr[j], acc[i][j], 0, 0, 0);
  }

  ushort* vb = vbf + (size_t)b * CC * LL;
#pragma unroll
  for (int i = 0; i < 4; ++i) {
#pragma unroll
    for (int r = 0; r < 4; ++r) {
      int c = c0 + wr + i * 16 + quad * 4 + r;
      float bias = bv[c];
#pragma unroll
      for (int j = 0; j < 4; ++j) {
        int l = l0 + wc + j * 16 + ln;
        vb[(size_t)c * LL + l] = f2bu(acc[i][j][r] + bias);
      }
    }
  }
}

// ---------------- fused scores (hi/lo MFMA) + softmax -> att fp32 + attbf bf16
// block: 16 att rows x 1024 cols; wave w owns cols [w*256, w*256+256)
__global__ __launch_bounds__(256) void scores_softmax_kernel(
    const float* __restrict__ qk, const ushort* __restrict__ kth,
    const ushort* __restrict__ ktl, float* __restrict__ att,
    ushort* __restrict__ attbf) {
  __shared__ float qs[32][17];
  __shared__ ushort kbuf[4][2][2048];  // [wave][hi/lo][64 cols x 32 k]  (32 KB)
  __shared__ float red[4][16];
  int b = blockIdx.y;
  int i0 = blockIdx.x * 16;
  int tid = threadIdx.x;
  int wave = tid >> 6, lane = tid & 63;
  int quad = lane >> 4, ln = lane & 15;

  // stage q tile [32 d][16 rows]
  const float* qb = qk + (size_t)b * 64 * LL;
  {
    int e0 = tid, e1 = tid + 256;
    qs[e0 >> 4][e0 & 15] = qb[(size_t)(e0 >> 4) * LL + i0 + (e0 & 15)];
    qs[e1 >> 4][e1 & 15] = qb[(size_t)(e1 >> 4) * LL + i0 + (e1 & 15)];
  }
  __syncthreads();

  // A fragments hi/lo: A[m=ln][k=quad*8+jj]
  bf16x8 ahi, alo;
  {
    union { bf16x8 v; ushort u[8]; } H, L;
#pragma unroll
    for (int jj = 0; jj < 8; ++jj) {
      float v = qs[quad * 8 + jj][ln];
      ushort hh = f2bu(v);
      H.u[jj] = hh;
      L.u[jj] = f2bu(v - bu2f(hh));
    }
    ahi = H.v;
    alo = L.v;
  }

  const ushort* khB = kth + (size_t)b * LL * 32;
  const ushort* klB = ktl + (size_t)b * LL * 32;
  ushort* lh = &kbuf[wave][0][0];
  ushort* llo = &kbuf[wave][1][0];

  f32x4 acc[16];
#pragma unroll
  for (int f = 0; f < 16; ++f) acc[f] = {0.f, 0.f, 0.f, 0.f};

  for (int ct = 0; ct < 4; ++ct) {
    int jt0 = wave * 16 + ct * 4;
    const ushort* gh = khB + (size_t)jt0 * 512;
    const ushort* gl = klB + (size_t)jt0 * 512;
#pragma unroll
    for (int t = 0; t < 4; ++t) {
      async_ld16(gh + (size_t)t * 512 + lane * 8, lh + t * 512);
      async_ld16(gl + (size_t)t * 512 + lane * 8, llo + t * 512);
    }
    asm volatile("s_waitcnt vmcnt(0)" ::: "memory");
#pragma unroll
    for (int t = 0; t < 4; ++t) {
      bf16x8 bh = *(const bf16x8*)&lh[t * 512 + lane * 8];
      bf16x8 bl = *(const bf16x8*)&llo[t * 512 + lane * 8];
      int f = ct * 4 + t;
      acc[f] = __builtin_amdgcn_mfma_f32_16x16x32_bf16(ahi, bh, acc[f], 0, 0, 0);
      acc[f] = __builtin_amdgcn_mfma_f32_16x16x32_bf16(ahi, bl, acc[f], 0, 0, 0);
      acc[f] = __builtin_amdgcn_mfma_f32_16x16x32_bf16(alo, bh, acc[f], 0, 0, 0);
    }
    asm volatile("" ::: "memory");  // keep staging of next chunk after these reads
  }

  // ---- row max over this wave's 256 cols
  float mrow[4];
#pragma unroll
  for (int r = 0; r < 4; ++r) {
    float m = acc[0][r];
#pragma unroll
    for (int f = 1; f < 16; ++f) m = fmaxf(m, acc[f][r]);
    mrow[r] = m;
  }
#pragma unroll
  for (int mask = 1; mask < 16; mask <<= 1)
#pragma unroll
    for (int r = 0; r < 4; ++r) mrow[r] = fmaxf(mrow[r], __shfl_xor(mrow[r], mask));
  if (ln == 0) {
#pragma unroll
    for (int r = 0; r < 4; ++r) red[wave][quad * 4 + r] = mrow[r];
  }
  __syncthreads();
  float gmax[4];
#pragma unroll
  for (int r = 0; r < 4; ++r)
    gmax[r] = fmaxf(fmaxf(red[0][quad * 4 + r], red[1][quad * 4 + r]),
                    fmaxf(red[2][quad * 4 + r], red[3][quad * 4 + r]));
  __syncthreads();

  // ---- exp + row sum
  float ssum[4] = {0.f, 0.f, 0.f, 0.f};
#pragma unroll
  for (int f = 0; f < 16; ++f)
#pragma unroll
    for (int r = 0; r < 4; ++r) {
      float e = __expf(acc[f][r] - gmax[r]);
      acc[f][r] = e;
      ssum[r] += e;
    }
#pragma unroll
  for (int mask = 1; mask < 16; mask <<= 1)
#pragma unroll
    for (int r = 0; r < 4; ++r) ssum[r] += __shfl_xor(ssum[r], mask);
  if (ln == 0) {
#pragma unroll
    for (int r = 0; r < 4; ++r) red[wave][quad * 4 + r] = ssum[r];
  }
  __syncthreads();
  float inv[4];
#pragma unroll
  for (int r = 0; r < 4; ++r)
    inv[r] = 1.0f / (red[0][quad * 4 + r] + red[1][quad * 4 + r] +
                     red[2][quad * 4 + r] + red[3][quad * 4 + r]);

  // ---- normalize + store
  float* attB = att + (size_t)b * LL * LL;
  ushort* attbfB = attbf + (size_t)b * LL * LL;
#pragma unroll
  for (int r = 0; r < 4; ++r) {
    size_t rowoff = (size_t)(i0 + quad * 4 + r) * LL;
#pragma unroll
    for (int f = 0; f < 16; ++f) {
      int col = wave * 256 + f * 16 + ln;
      float p = acc[f][r] * inv[r];
      attB[rowoff + col] = p;
      attbfB[rowoff + col] = f2bu(p);
    }
  }
}

// ------------- out[b][c][m] = gamma * sum_l v[c][l]*att[m][l] + x  (bf16 MFMA)
__global__ __launch_bounds__(256) void out_mfma_kernel(
    const ushort* __restrict__ vbf, const ushort* __restrict__ attbf,
    const float* __restrict__ x, const float* __restrict__ gamma,
    float* __restrict__ out) {
  __shared__ ushort As[128 * 32];
  __shared__ ushort Bs[128 * 32];
  int b = blockIdx.z;
  int c0 = blockIdx.y * 128;
  int m0 = blockIdx.x * 128;
  int tid = threadIdx.x;
  int wave = tid >> 6, lane = tid & 63;
  int quad = lane >> 4, ln = lane & 15;
  int wr = (wave >> 1) * 64;
  int wc = (wave & 1) * 64;

  const ushort* vb = vbf + (size_t)b * CC * LL;
  const ushort* ab = attbf + (size_t)b * LL * LL;

  int r0 = tid >> 2, r1 = r0 + 64;
  int cq = (tid & 3) * 8;
  ushort* lA0 = As + (size_t)(wave * 64) * 8;
  ushort* lA1 = As + (size_t)(256 + wave * 64) * 8;
  ushort* lB0 = Bs + (size_t)(wave * 64) * 8;
  ushort* lB1 = Bs + (size_t)(256 + wave * 64) * 8;

  f32x4 acc[4][4];
#pragma unroll
  for (int i = 0; i < 4; ++i)
#pragma unroll
    for (int j = 0; j < 4; ++j) acc[i][j] = {0.f, 0.f, 0.f, 0.f};

  for (int kt = 0; kt < LL; kt += 32) {
    __syncthreads();
    async_ld16(vb + (size_t)(c0 + r0) * LL + kt + cq, lA0);
    async_ld16(vb + (size_t)(c0 + r1) * LL + kt + cq, lA1);
    async_ld16(ab + (size_t)(m0 + r0) * LL + kt + cq, lB0);
    async_ld16(ab + (size_t)(m0 + r1) * LL + kt + cq, lB1);
    __syncthreads();

    bf16x8 af[4], bfr[4];
#pragma unroll
    for (int i = 0; i < 4; ++i)
      af[i] = *(const bf16x8*)&As[(size_t)(wr + i * 16 + ln) * 32 + quad * 8];
#pragma unroll
    for (int j = 0; j < 4; ++j)
      bfr[j] = *(const bf16x8*)&Bs[(size_t)(wc + j * 16 + ln) * 32 + quad * 8];
#pragma unroll
    for (int i = 0; i < 4; ++i)
#pragma unroll
      for (int j = 0; j < 4; ++j)
        acc[i][j] = __builtin_amdgcn_mfma_f32_16x16x32_bf16(af[i], bfr[j], acc[i][j], 0, 0, 0);
  }

  float g = gamma[0];
  const float* xb = x + (size_t)b * CC * LL;
  float* ob = out + (size_t)b * CC * LL;
#pragma unroll
  for (int i = 0; i < 4; ++i) {
#pragma unroll
    for (int r = 0; r < 4; ++r) {
      int c = c0 + wr + i * 16 + quad * 4 + r;
#pragma unroll
      for (int j = 0; j < 4; ++j) {
        int m = m0 + wc + j * 16 + ln;
        size_t idx = (size_t)c * LL + m;
        ob[idx] = fmaf(g, acc[i][j][r], xb[idx]);
      }
    }
  }
}

extern "C" void kernel_launch(void* const* d_in, const int* in_sizes, int n_in,
                              void* d_out, int out_size, void* d_ws, size_t ws_size,
                              hipStream_t stream) {
  const float* x = (const float*)d_in[0];
  const float* Wq = (const float*)d_in[1];
  const float* bq = (const float*)d_in[2];
  const float* Wk = (const float*)d_in[3];
  const float* bk = (const float*)d_in[4];
  const float* Wv = (const float*)d_in[5];
  const float* bv = (const float*)d_in[6];
  const float* gamma = (const float*)d_in[7];

  float* out = (float*)d_out;
  float* att = out + (size_t)BB * CC * LL;

  float* wsf = (float*)d_ws;
  float* Wcat = wsf + WCAT_OFF;
  float* bcat = wsf + BCAT_OFF;
  float* qk = wsf + QK_OFF;
  ushort* usbase = (ushort*)(wsf + US_BASE);
  ushort* vbf = usbase + VBF_OFF;
  ushort* attbf = usbase + ATTBF_OFF;
  ushort* Wvbf = usbase + WVBF_OFF;
  ushort* xT = usbase + XT_OFF;
  ushort* kth = usbase + KTH_OFF;
  ushort* ktl = usbase + KTL_OFF;

  pack_w_kernel<<<dim3(OTOT), dim3(CC), 0, stream>>>(Wq, bq, Wk, bk, Wv, bv, Wcat, bcat, Wvbf);
  xT_kernel<<<dim3(LL / 64, CC / 64, BB), dim3(256), 0, stream>>>(x, xT);
  proj_qk_kernel<<<dim3(LL / 64, 1, BB), dim3(256), 0, stream>>>(x, Wcat, bcat, qk);
  kT_pack_kernel<<<dim3(4, BB), dim3(256), 0, stream>>>(qk, kth, ktl);
  v_mfma_kernel<<<dim3(LL / 128, CC / 128, BB), dim3(256), 0, stream>>>(Wvbf, xT, bv, vbf);
  scores_softmax_kernel<<<dim3(LL / 16, BB), dim3(256), 0, stream>>>(qk, kth, ktl, att, attbf);
  out_mfma_kernel<<<dim3(LL / 128, CC / 128, BB), dim3(256), 0, stream>>>(vbf, attbf, x, gamma, out);
}